// Round 1
// baseline (358.520 us; speedup 1.0000x reference)
//
#include <hip/hip_runtime.h>
#include <hip/hip_bf16.h>
#include <stdint.h>

// Problem constants
#define NB 2
#define NS 2048
#define ND 1024
#define NH 16
#define NDK 64
#define NM (NB*NS)   // 4096 rows

using bf16x8 = __attribute__((ext_vector_type(8))) short;   // 8 bf16 (4 VGPRs)
using f32x4  = __attribute__((ext_vector_type(4))) float;   // 4 fp32

__device__ __forceinline__ unsigned short f2bf(float f){
  unsigned u = __float_as_uint(f);
  u += 0x7fffu + ((u>>16)&1u);          // RNE
  return (unsigned short)(u>>16);
}

__device__ __forceinline__ void gload_lds16(const void* g, void* l){
  __builtin_amdgcn_global_load_lds((const __attribute__((address_space(1))) void*)g,
                                   (__attribute__((address_space(3))) void*)l, 16, 0, 0);
}

// ---------------- fp32 -> bf16 cast (vectorized float4 -> ushort4) ----------------
__global__ __launch_bounds__(256) void cast_bf16(const float* __restrict__ src,
                                                 unsigned short* __restrict__ dst, int n4){
  int i = blockIdx.x*256 + threadIdx.x;
  if (i < n4){
    float4 v = ((const float4*)src)[i];
    ushort4 o;
    o.x = f2bf(v.x); o.y = f2bf(v.y); o.z = f2bf(v.z); o.w = f2bf(v.w);
    ((ushort4*)dst)[i] = o;
  }
}

// ---------------- 128x128 bf16 GEMM core (m97 structure) ----------------
// C[m,n] = sum_k A[m,k]*W[n,k]   A:[4096][1024] bf16, W:[1024][1024] bf16 (B^T form)
// mode 0: store bf16 to qh/kh layout [b,h,s,dk]
// mode 1: store bf16 to vT layout [b,h,dk,s]
// mode 2: store fp32 row-major [m][1024]
__device__ void gemm128_core(const short* __restrict__ A, const short* __restrict__ W,
                             void* __restrict__ out, int mode){
  __shared__ short lsA[2][4096];   // [buf][128 rows x 32 k] linear (global_load_lds dest)
  __shared__ short lsB[2][4096];
  const int tid = threadIdx.x;
  const int m0 = blockIdx.y*128, n0 = blockIdx.x*128;
  const short* gA = A + (size_t)m0*1024;
  const short* gB = W + (size_t)n0*1024;
  const int srow = tid>>2, scol = (tid&3)*8;      // staging: 4 threads/row, 16B each
  const int w = tid>>6, lane = tid&63, lr = lane&15, lk = lane>>4;
  const int wm = w>>1, wn = w&1;                  // 2x2 wave grid, 64x64 per wave

  f32x4 acc[4][4];
  #pragma unroll
  for (int i=0;i<4;++i)
    #pragma unroll
    for (int j=0;j<4;++j) acc[i][j] = (f32x4){0.f,0.f,0.f,0.f};

  // prologue: stage k-step 0 into buf 0
  #pragma unroll
  for (int r=0;r<2;++r){
    gload_lds16(gA + (size_t)(r*64+srow)*1024 + scol, &lsA[0][(r*256+tid)*8]);
    gload_lds16(gB + (size_t)(r*64+srow)*1024 + scol, &lsB[0][(r*256+tid)*8]);
  }
  int cur = 0;
  for (int ks=0; ks<32; ++ks){
    __syncthreads();                               // drains vmcnt -> buf[cur] ready
    if (ks+1 < 32){                                // issue next tile into other buffer
      const int k0 = (ks+1)*32;
      #pragma unroll
      for (int r=0;r<2;++r){
        gload_lds16(gA + (size_t)(r*64+srow)*1024 + k0 + scol, &lsA[cur^1][(r*256+tid)*8]);
        gload_lds16(gB + (size_t)(r*64+srow)*1024 + k0 + scol, &lsB[cur^1][(r*256+tid)*8]);
      }
    }
    bf16x8 af[4], bfr[4];
    #pragma unroll
    for (int i=0;i<4;++i){
      af[i]  = *(const bf16x8*)&lsA[cur][(wm*64+i*16+lr)*32 + lk*8];
      bfr[i] = *(const bf16x8*)&lsB[cur][(wn*64+i*16+lr)*32 + lk*8];
    }
    #pragma unroll
    for (int i=0;i<4;++i)
      #pragma unroll
      for (int j=0;j<4;++j)
        acc[i][j] = __builtin_amdgcn_mfma_f32_16x16x32_bf16(af[i], bfr[j], acc[i][j], 0,0,0);
    cur ^= 1;
  }
  // epilogue: C/D layout col=lane&15, row=(lane>>4)*4+r
  #pragma unroll
  for (int i=0;i<4;++i)
    #pragma unroll
    for (int j=0;j<4;++j)
      #pragma unroll
      for (int r=0;r<4;++r){
        const int m = m0 + wm*64 + i*16 + lk*4 + r;
        const int n = n0 + wn*64 + j*16 + lr;
        const float v = acc[i][j][r];
        if (mode == 2){
          ((float*)out)[(size_t)m*1024 + n] = v;
        } else {
          const int b = m>>11, s = m&2047, h = n>>6, dk = n&63;
          size_t addr;
          if (mode == 0) addr = (((size_t)(b*NH+h))*NS + s)*NDK + dk;     // [b,h,s,dk]
          else           addr = (((size_t)(b*NH+h))*NDK + dk)*NS + s;     // [b,h,dk,s]
          ((unsigned short*)out)[addr] = f2bf(v);
        }
      }
}

__global__ __launch_bounds__(256) void gemm_qkv(const short* __restrict__ Xbf, const short* __restrict__ Wbf,
                                                unsigned short* qh, unsigned short* kh, unsigned short* vT){
  const int z = blockIdx.z;
  const short* A = Xbf + (size_t)z*NM*ND;
  const short* W = Wbf + (size_t)z*ND*ND;
  void* out = (z==0) ? (void*)qh : (z==1) ? (void*)kh : (void*)vT;
  gemm128_core(A, W, out, (z==2) ? 1 : 0);
}

__global__ __launch_bounds__(256) void gemm_out(const short* __restrict__ Attn, const short* __restrict__ Wo,
                                                float* proj){
  gemm128_core(Attn, Wo, proj, 2);
}

// ---------------- flash attention ----------------
// grid: 1024 blocks = (b,h,qblk). 4 waves/block, each wave owns 16 q-rows.
// K,V read directly from global (L2-fits, 256KB/head). P staged per-wave in swizzled LDS.
__global__ __launch_bounds__(256) void attn_k(const short* __restrict__ qh, const short* __restrict__ kh,
                                              const short* __restrict__ vT, const int* __restrict__ mask,
                                              unsigned short* __restrict__ attn){
  __shared__ short plds[4][16*64];   // per-wave 16x64 P tile, XOR-swizzled ^((row&7)<<4)
  const int bid = blockIdx.x;
  const int qblk = bid & 31, h = (bid>>5)&15, b = bid>>9;
  const int tid = threadIdx.x, w = tid>>6, lane = tid&63, lr = lane&15, lk = lane>>4;
  const int bh = b*NH + h;
  const int q0 = qblk*64 + w*16;

  const short* qbase = qh + ((size_t)bh*NS + q0 + lr)*NDK;
  const bf16x8 aq0 = *(const bf16x8*)(qbase + lk*8);
  const bf16x8 aq1 = *(const bf16x8*)(qbase + 32 + lk*8);

  f32x4 o[4];
  #pragma unroll
  for (int i=0;i<4;++i) o[i] = (f32x4){0.f,0.f,0.f,0.f};
  float mrun[4], lrun[4];
  #pragma unroll
  for (int r=0;r<4;++r){ mrun[r] = -1e30f; lrun[r] = 0.f; }

  const short* kbase = kh + (size_t)bh*NS*NDK;
  const short* vbase = vT + (size_t)bh*NDK*NS;

  for (int kt=0; kt<32; ++kt){
    const int kv0 = kt*64;
    // S = (Q K^T) * 1/8, with mask
    f32x4 s[4];
    #pragma unroll
    for (int nn=0;nn<4;++nn){
      const short* kp = kbase + (size_t)(kv0 + nn*16 + lr)*NDK;
      const bf16x8 bk0 = *(const bf16x8*)(kp + lk*8);
      const bf16x8 bk1 = *(const bf16x8*)(kp + 32 + lk*8);
      f32x4 a = (f32x4){0.f,0.f,0.f,0.f};
      a = __builtin_amdgcn_mfma_f32_16x16x32_bf16(aq0, bk0, a, 0,0,0);
      a = __builtin_amdgcn_mfma_f32_16x16x32_bf16(aq1, bk1, a, 0,0,0);
      const int mv = mask[b*NS + kv0 + nn*16 + lr];
      #pragma unroll
      for (int r=0;r<4;++r) s[nn][r] = mv ? a[r]*0.125f : -1e30f;
    }
    // online softmax (rows = lk*4+r, reduce over 16 lanes of subgroup)
    float mnew[4], fac[4], psum[4];
    #pragma unroll
    for (int r=0;r<4;++r){
      float rm = fmaxf(fmaxf(s[0][r],s[1][r]), fmaxf(s[2][r],s[3][r]));
      #pragma unroll
      for (int off=1; off<16; off<<=1) rm = fmaxf(rm, __shfl_xor(rm, off, 64));
      mnew[r] = fmaxf(mrun[r], rm);
      fac[r]  = __expf(mrun[r] - mnew[r]);
      lrun[r] *= fac[r];
      psum[r] = 0.f;
    }
    #pragma unroll
    for (int nn=0;nn<4;++nn){
      #pragma unroll
      for (int r=0;r<4;++r){
        const float p = __expf(s[nn][r] - mnew[r]);
        psum[r] += p;
        const int row = lk*4 + r, col = nn*16 + lr;
        const int boff = (row*128 + col*2) ^ ((row&7)<<4);
        *(short*)((char*)&plds[w][0] + boff) = (short)f2bf(p);
      }
    }
    #pragma unroll
    for (int r=0;r<4;++r){
      float ps = psum[r];
      #pragma unroll
      for (int off=1; off<16; off<<=1) ps += __shfl_xor(ps, off, 64);
      lrun[r] += ps;
      mrun[r] = mnew[r];
      #pragma unroll
      for (int nn=0;nn<4;++nn) o[nn][r] *= fac[r];
    }
    // PV: A = P (from swizzled LDS), B = V^T rows (contiguous in kv)
    const bf16x8 pa0 = *(const bf16x8*)((char*)&plds[w][0] + ((lr*128 +  0 + lk*16) ^ ((lr&7)<<4)));
    const bf16x8 pa1 = *(const bf16x8*)((char*)&plds[w][0] + ((lr*128 + 64 + lk*16) ^ ((lr&7)<<4)));
    #pragma unroll
    for (int dn=0;dn<4;++dn){
      const short* vp = vbase + (size_t)(dn*16 + lr)*NS + kv0;
      const bf16x8 bv0 = *(const bf16x8*)(vp + lk*8);
      const bf16x8 bv1 = *(const bf16x8*)(vp + 32 + lk*8);
      o[dn] = __builtin_amdgcn_mfma_f32_16x16x32_bf16(pa0, bv0, o[dn], 0,0,0);
      o[dn] = __builtin_amdgcn_mfma_f32_16x16x32_bf16(pa1, bv1, o[dn], 0,0,0);
    }
  }
  // epilogue: normalize, store bf16 to concat layout [b, s, h*64+dk]
  #pragma unroll
  for (int dn=0;dn<4;++dn)
    #pragma unroll
    for (int r=0;r<4;++r){
      const float v = o[dn][r] / lrun[r];
      const int q = q0 + lk*4 + r;
      attn[((size_t)b*NS + q)*ND + h*NDK + dn*16 + lr] = f2bf(v);
    }
}

// ---------------- residual + LayerNorm (1 wave per row) ----------------
__global__ __launch_bounds__(256) void ln_k(const float* __restrict__ proj, const float* __restrict__ Qin,
                                            const float* __restrict__ gamma, const float* __restrict__ beta,
                                            float* __restrict__ out){
  const int row = blockIdx.x*4 + (threadIdx.x>>6);
  const int lane = threadIdx.x & 63;
  const float4* pp = (const float4*)(proj + (size_t)row*ND);
  const float4* qq = (const float4*)(Qin + (size_t)row*ND);
  float4 x[4];
  float sum = 0.f;
  #pragma unroll
  for (int i=0;i<4;++i){
    const float4 a = pp[lane + i*64];
    const float4 bq = qq[lane + i*64];
    x[i].x = a.x+bq.x; x[i].y = a.y+bq.y; x[i].z = a.z+bq.z; x[i].w = a.w+bq.w;
    sum += x[i].x + x[i].y + x[i].z + x[i].w;
  }
  #pragma unroll
  for (int off=32; off>=1; off>>=1) sum += __shfl_xor(sum, off, 64);
  const float mu = sum * (1.f/1024.f);
  float vs = 0.f;
  #pragma unroll
  for (int i=0;i<4;++i){
    float d0=x[i].x-mu, d1=x[i].y-mu, d2=x[i].z-mu, d3=x[i].w-mu;
    vs += d0*d0 + d1*d1 + d2*d2 + d3*d3;
  }
  #pragma unroll
  for (int off=32; off>=1; off>>=1) vs += __shfl_xor(vs, off, 64);
  const float rstd = rsqrtf(vs*(1.f/1024.f) + 1e-5f);
  #pragma unroll
  for (int i=0;i<4;++i){
    const float4 g  = ((const float4*)gamma)[lane + i*64];
    const float4 be = ((const float4*)beta)[lane + i*64];
    float4 y;
    y.x = (x[i].x-mu)*rstd*g.x + be.x;
    y.y = (x[i].y-mu)*rstd*g.y + be.y;
    y.z = (x[i].z-mu)*rstd*g.z + be.z;
    y.w = (x[i].w-mu)*rstd*g.w + be.w;
    ((float4*)(out + (size_t)row*ND))[lane + i*64] = y;
  }
}

// ---------------- launch ----------------
// ws layout (64 MB total):
//   [0,8MB)   Wbf: Wq,Wk,Wv,Wo bf16 (1M elems each)
//   [8,32MB)  Xbf: Qbf,Kbf,Vbf (4M elems each); proj f32 (16MB) aliases [8,24MB) later
//   [32,40)   qh bf16 [b,h,s,dk]
//   [40,48)   kh bf16 [b,h,s,dk]
//   [48,56)   vT bf16 [b,h,dk,s]
//   [56,64)   attn bf16 [b,s,d]
extern "C" void kernel_launch(void* const* d_in, const int* in_sizes, int n_in,
                              void* d_out, int out_size, void* d_ws, size_t ws_size,
                              hipStream_t stream){
  const float* Q    = (const float*)d_in[0];
  const float* K    = (const float*)d_in[1];
  const float* V    = (const float*)d_in[2];
  const int*   mask = (const int*)  d_in[3];
  const float* Wq   = (const float*)d_in[4];
  const float* Wk   = (const float*)d_in[5];
  const float* Wv   = (const float*)d_in[6];
  const float* Wo   = (const float*)d_in[7];
  const float* gam  = (const float*)d_in[8];
  const float* bet  = (const float*)d_in[9];
  float* out = (float*)d_out;
  char* ws = (char*)d_ws;

  unsigned short* Wbf  = (unsigned short*)(ws);
  unsigned short* Xbf  = (unsigned short*)(ws + (size_t)(8u<<20));
  unsigned short* qhp  = (unsigned short*)(ws + (size_t)(32u<<20));
  unsigned short* khp  = (unsigned short*)(ws + (size_t)(40u<<20));
  unsigned short* vTp  = (unsigned short*)(ws + (size_t)(48u<<20));
  unsigned short* attb = (unsigned short*)(ws + (size_t)(56u<<20));
  float* proj = (float*)(ws + (size_t)(8u<<20));   // aliases Xbf (dead by then)

  // casts
  cast_bf16<<<4096,256,0,stream>>>(Q, Xbf,                 1<<20);
  cast_bf16<<<4096,256,0,stream>>>(K, Xbf + (1u<<22),      1<<20);
  cast_bf16<<<4096,256,0,stream>>>(V, Xbf + (2u<<22),      1<<20);
  cast_bf16<<<1024,256,0,stream>>>(Wq, Wbf,                1<<18);
  cast_bf16<<<1024,256,0,stream>>>(Wk, Wbf + (1u<<20),     1<<18);
  cast_bf16<<<1024,256,0,stream>>>(Wv, Wbf + (2u<<20),     1<<18);
  cast_bf16<<<1024,256,0,stream>>>(Wo, Wbf + (3u<<20),     1<<18);

  // fused Q/K/V projections (768 blocks = 3 GEMMs in one dispatch)
  gemm_qkv<<<dim3(8,32,3),256,0,stream>>>((const short*)Xbf, (const short*)Wbf, qhp, khp, vTp);

  // flash attention
  attn_k<<<1024,256,0,stream>>>((const short*)qhp, (const short*)khp, (const short*)vTp, mask, attb);

  // output projection
  gemm_out<<<dim3(8,32),256,0,stream>>>((const short*)attb, (const short*)(Wbf + (3u<<20)), proj);

  // residual + layernorm
  ln_k<<<1024,256,0,stream>>>(proj, Q, gam, bet, out);
}

// Round 2
// 245.933 us; speedup vs baseline: 1.4578x; 1.4578x over previous
//
#include <hip/hip_runtime.h>
#include <hip/hip_bf16.h>
#include <stdint.h>

// Problem constants
#define NB 2
#define NS 2048
#define ND 1024
#define NH 16
#define NDK 64
#define NM (NB*NS)   // 4096 rows

using bf16x8 = __attribute__((ext_vector_type(8))) short;   // 8 bf16 (4 VGPRs)
using f32x4  = __attribute__((ext_vector_type(4))) float;   // 4 fp32
using f32x16 = __attribute__((ext_vector_type(16))) float;  // 16 fp32
using u32x4  = __attribute__((ext_vector_type(4))) unsigned;

__device__ __forceinline__ unsigned short f2bf(float f){
  unsigned u = __float_as_uint(f);
  u += 0x7fffu + ((u>>16)&1u);          // RNE
  return (unsigned short)(u>>16);
}

__device__ __forceinline__ void gload_lds16(const void* g, void* l){
  __builtin_amdgcn_global_load_lds((const __attribute__((address_space(1))) void*)g,
                                   (__attribute__((address_space(3))) void*)l, 16, 0, 0);
}

__device__ __forceinline__ float fexp2(float x){
#if __has_builtin(__builtin_amdgcn_exp2f)
  return __builtin_amdgcn_exp2f(x);
#else
  return __expf(x * 0.69314718056f);
#endif
}

__device__ __forceinline__ unsigned cvtpk_bf16(float lo, float hi){
  unsigned r;
  asm("v_cvt_pk_bf16_f32 %0, %1, %2" : "=v"(r) : "v"(lo), "v"(hi));
  return r;
}

// permlane32_swap: given a (this lane's low-half word) and b (this lane's high-half word),
// returns {w_lo, w_hi}: w_lo = [a.lanes0-31 | b.lanes0-31 shifted up], w_hi = [a.lanes32-63 | b.lanes32-63]
__device__ __forceinline__ void swap32(unsigned &a, unsigned &b){
#if __has_builtin(__builtin_amdgcn_permlane32_swap)
  auto rr = __builtin_amdgcn_permlane32_swap((int)a, (int)b, false, false);
  a = (unsigned)rr[0]; b = (unsigned)rr[1];
#else
  const bool lo = (threadIdx.x & 32) == 0;
  unsigned sa = (unsigned)__shfl_xor((int)a, 32, 64);
  unsigned sb = (unsigned)__shfl_xor((int)b, 32, 64);
  unsigned na = lo ? a : sb;
  unsigned nb = lo ? sa : b;
  a = na; b = nb;
#endif
}

__device__ __forceinline__ f32x16 mfma32(bf16x8 a, bf16x8 b, f32x16 c){
  return __builtin_amdgcn_mfma_f32_32x32x16_bf16(a, b, c, 0, 0, 0);
}

// ---------------- fp32 -> bf16 cast ----------------
__global__ __launch_bounds__(256) void cast_bf16(const float* __restrict__ src,
                                                 unsigned short* __restrict__ dst, int n4){
  int i = blockIdx.x*256 + threadIdx.x;
  if (i < n4){
    float4 v = ((const float4*)src)[i];
    ushort4 o;
    o.x = f2bf(v.x); o.y = f2bf(v.y); o.z = f2bf(v.z); o.w = f2bf(v.w);
    ((ushort4*)dst)[i] = o;
  }
}

// ---------------- mask -> bitmask (1 bit per kv position) ----------------
__global__ __launch_bounds__(256) void maskbits_k(const int* __restrict__ mask, unsigned* __restrict__ pm){
  int t = blockIdx.x*256 + threadIdx.x;   // t over [0, 4096)
  unsigned long long bal = __ballot(mask[t] != 0);
  if ((t & 63) == 0){
    pm[t>>5]     = (unsigned)bal;
    pm[(t>>5)+1] = (unsigned)(bal>>32);
  }
}

// ---------------- 128x128 bf16 GEMM core (m97 structure) ----------------
__device__ void gemm128_core(const short* __restrict__ A, const short* __restrict__ W,
                             void* __restrict__ out, int mode){
  __shared__ short lsA[2][4096];
  __shared__ short lsB[2][4096];
  const int tid = threadIdx.x;
  const int m0 = blockIdx.y*128, n0 = blockIdx.x*128;
  const short* gA = A + (size_t)m0*1024;
  const short* gB = W + (size_t)n0*1024;
  const int srow = tid>>2, scol = (tid&3)*8;
  const int w = tid>>6, lane = tid&63, lr = lane&15, lk = lane>>4;
  const int wm = w>>1, wn = w&1;

  f32x4 acc[4][4];
  #pragma unroll
  for (int i=0;i<4;++i)
    #pragma unroll
    for (int j=0;j<4;++j) acc[i][j] = (f32x4){0.f,0.f,0.f,0.f};

  #pragma unroll
  for (int r=0;r<2;++r){
    gload_lds16(gA + (size_t)(r*64+srow)*1024 + scol, &lsA[0][(r*256+tid)*8]);
    gload_lds16(gB + (size_t)(r*64+srow)*1024 + scol, &lsB[0][(r*256+tid)*8]);
  }
  int cur = 0;
  for (int ks=0; ks<32; ++ks){
    __syncthreads();
    if (ks+1 < 32){
      const int k0 = (ks+1)*32;
      #pragma unroll
      for (int r=0;r<2;++r){
        gload_lds16(gA + (size_t)(r*64+srow)*1024 + k0 + scol, &lsA[cur^1][(r*256+tid)*8]);
        gload_lds16(gB + (size_t)(r*64+srow)*1024 + k0 + scol, &lsB[cur^1][(r*256+tid)*8]);
      }
    }
    bf16x8 af[4], bfr[4];
    #pragma unroll
    for (int i=0;i<4;++i){
      af[i]  = *(const bf16x8*)&lsA[cur][(wm*64+i*16+lr)*32 + lk*8];
      bfr[i] = *(const bf16x8*)&lsB[cur][(wn*64+i*16+lr)*32 + lk*8];
    }
    #pragma unroll
    for (int i=0;i<4;++i)
      #pragma unroll
      for (int j=0;j<4;++j)
        acc[i][j] = __builtin_amdgcn_mfma_f32_16x16x32_bf16(af[i], bfr[j], acc[i][j], 0,0,0);
    cur ^= 1;
  }
  #pragma unroll
  for (int i=0;i<4;++i)
    #pragma unroll
    for (int j=0;j<4;++j)
      #pragma unroll
      for (int r=0;r<4;++r){
        const int m = m0 + wm*64 + i*16 + lk*4 + r;
        const int n = n0 + wn*64 + j*16 + lr;
        const float v = acc[i][j][r];
        if (mode == 2){
          ((float*)out)[(size_t)m*1024 + n] = v;
        } else {
          const int b = m>>11, s = m&2047, h = n>>6, dk = n&63;
          size_t addr;
          if (mode == 0) addr = (((size_t)(b*NH+h))*NS + s)*NDK + dk;     // [b,h,s,dk]
          else           addr = (((size_t)(b*NH+h))*NDK + dk)*NS + s;     // [b,h,dk,s]
          ((unsigned short*)out)[addr] = f2bf(v);
        }
      }
}

__global__ __launch_bounds__(256) void gemm_qkv(const short* __restrict__ Xbf, const short* __restrict__ Wbf,
                                                unsigned short* qh, unsigned short* kh, unsigned short* vT){
  const int z = blockIdx.z;
  const short* A = Xbf + (size_t)z*NM*ND;
  const short* W = Wbf + (size_t)z*ND*ND;
  void* out = (z==0) ? (void*)qh : (z==1) ? (void*)kh : (void*)vT;
  gemm128_core(A, W, out, (z==2) ? 1 : 0);
}

__global__ __launch_bounds__(256) void gemm_out(const short* __restrict__ Attn, const short* __restrict__ Wo,
                                                float* proj){
  gemm128_core(Attn, Wo, proj, 2);
}

// ---------------- flash attention, swapped-QK 32x32 structure ----------------
// Grid: 256 blocks = (b, h, qblk-of-256). 8 warps/block, each warp owns 32 q rows.
// Per lane: q = lane&31 is lane-local for S^T and O^T -> softmax state is scalar per lane.
__global__ __launch_bounds__(512) void attn_k(const short* __restrict__ qh, const short* __restrict__ kh,
                                              const short* __restrict__ vT, const unsigned* __restrict__ pm,
                                              unsigned short* __restrict__ attn){
  __shared__ unsigned short eplds[8][2048];   // per-warp 32x64 bf16 transpose area (4KB)
  const int bid = blockIdx.x;
  const int qb = bid & 7, h = (bid>>3)&15, b = bid>>7;
  const int tid = threadIdx.x, w = tid>>6, lane = tid&63;
  const int ql = lane & 31, hi = lane>>5;
  const int bh = b*NH + h;
  const int q0 = qb*256 + w*32;
  const float C2 = 0.18033688f;   // 0.125 * log2(e)

  // Q as B-fragments (stays in regs): B[k=dk][n=q], lane holds Q[q0+ql][kp*16 + hi*8 + j]
  const short* qrow = qh + ((size_t)bh*NS + q0 + ql)*NDK + hi*8;
  bf16x8 qf[4];
  #pragma unroll
  for (int kp=0;kp<4;++kp) qf[kp] = *(const bf16x8*)(qrow + kp*16);

  const short* krow = kh + ((size_t)bh*NS + ql)*NDK + hi*8;   // + kv*NDK per tile
  const short* vrow = vT + ((size_t)bh*NDK + ql)*NS + hi*8;   // + dh*32*NS + kv per tile

  f32x16 o0, o1;
  #pragma unroll
  for (int r=0;r<16;++r){ o0[r]=0.f; o1[r]=0.f; }
  float mrun = -1e30f, lrun = 0.f;

  for (int kt=0; kt<32; ++kt){
    const int kv0 = kt*64;
    // prefetch K (8x16B) and V (8x16B) fragments
    bf16x8 kf[8], vf[8];
    #pragma unroll
    for (int kvh=0;kvh<2;++kvh)
      #pragma unroll
      for (int kp=0;kp<4;++kp)
        kf[kvh*4+kp] = *(const bf16x8*)(krow + (size_t)(kv0 + kvh*32)*NDK + kp*16);
    #pragma unroll
    for (int dh=0;dh<2;++dh)
      #pragma unroll
      for (int c=0;c<4;++c)
        vf[dh*4+c] = *(const bf16x8*)(vrow + (size_t)dh*32*NS + kv0 + c*16);
    const unsigned mw0 = pm[(b<<6) + kt*2], mw1 = pm[(b<<6) + kt*2 + 1];
    const bool allm = (mw0 & mw1) == 0xffffffffu;

    // S^T = K . Q^T  (raw, unscaled): s0 = kv rows [0,32), s1 = [32,64)
    f32x16 s0, s1;
    #pragma unroll
    for (int r=0;r<16;++r){ s0[r]=0.f; s1[r]=0.f; }
    #pragma unroll
    for (int kp=0;kp<4;++kp){
      s0 = mfma32(kf[kp],   qf[kp], s0);
      s1 = mfma32(kf[4+kp], qf[kp], s1);
    }

    // tile max (tree) over this lane's 32 values, then combine with partner lane (^32)
    float t[16];
    #pragma unroll
    for (int r=0;r<16;++r) t[r] = fmaxf(s0[r], s1[r]);
    #pragma unroll
    for (int st=8; st>=1; st>>=1)
      #pragma unroll
      for (int r=0;r<st;++r) t[r] = fmaxf(t[r], t[r+st]);
    float tm = fmaxf(t[0], __shfl_xor(t[0], 32, 64));

    const float mnew = fmaxf(mrun, tm);
    const float fac  = fexp2((mrun - mnew)*C2);
    mrun = mnew;
    const float nb = mnew*C2;
    #pragma unroll
    for (int r=0;r<16;++r){ o0[r]*=fac; o1[r]*=fac; }
    lrun *= fac;

    float psum = 0.f;
    // per 32-kv half: exp -> pack bf16 pairs -> permlane swap -> PV mfma
    #pragma unroll
    for (int kvh=0; kvh<2; ++kvh){
      const f32x16& ss = kvh ? s1 : s0;
      const unsigned mw = kvh ? mw1 : mw0;
      unsigned pwd[8];
      float ps0 = 0.f, ps1 = 0.f;
      #pragma unroll
      for (int i=0;i<8;++i){
        const int bp0 = ((2*i)&3) + 8*((2*i)>>2);   // {0,2,8,10,16,18,24,26}
        float p0 = fexp2(ss[2*i]*C2   - nb);
        float p1 = fexp2(ss[2*i+1]*C2 - nb);
        if (!allm){
          p0 = ((mw >> (bp0     + 4*hi)) & 1u) ? p0 : 0.f;
          p1 = ((mw >> (bp0 + 1 + 4*hi)) & 1u) ? p1 : 0.f;
        }
        ps0 += p0; ps1 += p1;
        pwd[i] = cvtpk_bf16(p0, p1);
      }
      psum += ps0 + ps1;
      // redistribute: swap(P0,P2)->chunk0 w0,w2; swap(P1,P3)->chunk0 w1,w3; P4..P7 -> chunk1
      swap32(pwd[0], pwd[2]);
      swap32(pwd[1], pwd[3]);
      swap32(pwd[4], pwd[6]);
      swap32(pwd[5], pwd[7]);
      u32x4 c0w = {pwd[0], pwd[1], pwd[2], pwd[3]};
      u32x4 c1w = {pwd[4], pwd[5], pwd[6], pwd[7]};
      bf16x8 pf0 = __builtin_bit_cast(bf16x8, c0w);
      bf16x8 pf1 = __builtin_bit_cast(bf16x8, c1w);
      // O^T += V^T . P^T   (chunks c = 2*kvh, 2*kvh+1)
      o0 = mfma32(vf[0*4 + 2*kvh],     pf0, o0);
      o1 = mfma32(vf[1*4 + 2*kvh],     pf0, o1);
      o0 = mfma32(vf[0*4 + 2*kvh + 1], pf1, o0);
      o1 = mfma32(vf[1*4 + 2*kvh + 1], pf1, o1);
    }
    psum += __shfl_xor(psum, 32, 64);
    lrun += psum;
  }

  // epilogue: O^T -> LDS (swizzled, packed pairs) -> coalesced global store of O[q][d]
  const float inv = 1.f / lrun;
  unsigned short* ep = &eplds[w][0];
  #pragma unroll
  for (int dh=0; dh<2; ++dh){
    const f32x16& oo = dh ? o1 : o0;
    #pragma unroll
    for (int i=0;i<8;++i){
      const int d0 = ((2*i)&3) + 8*((2*i)>>2) + 4*hi + dh*32;  // even, consecutive pair (d0, d0+1)
      const unsigned pk = cvtpk_bf16(oo[2*i]*inv, oo[2*i+1]*inv);
      *(unsigned*)((char*)ep + (((ql*128) + d0*2) ^ ((ql&7)<<4))) = pk;
    }
  }
  __syncthreads();
  #pragma unroll
  for (int seg=0; seg<4; ++seg){
    const int qq = seg*8 + (lane>>3), dc = (lane&7)*8;
    bf16x8 vv = *(const bf16x8*)((char*)ep + (((qq*128) + dc*2) ^ ((qq&7)<<4)));
    *(bf16x8*)(attn + ((size_t)b*NS + q0 + qq)*ND + h*NDK + dc) = vv;
  }
}

// ---------------- residual + LayerNorm (1 wave per row) ----------------
__global__ __launch_bounds__(256) void ln_k(const float* __restrict__ proj, const float* __restrict__ Qin,
                                            const float* __restrict__ gamma, const float* __restrict__ beta,
                                            float* __restrict__ out){
  const int row = blockIdx.x*4 + (threadIdx.x>>6);
  const int lane = threadIdx.x & 63;
  const float4* pp = (const float4*)(proj + (size_t)row*ND);
  const float4* qq = (const float4*)(Qin + (size_t)row*ND);
  float4 x[4];
  float sum = 0.f;
  #pragma unroll
  for (int i=0;i<4;++i){
    const float4 a = pp[lane + i*64];
    const float4 bq = qq[lane + i*64];
    x[i].x = a.x+bq.x; x[i].y = a.y+bq.y; x[i].z = a.z+bq.z; x[i].w = a.w+bq.w;
    sum += x[i].x + x[i].y + x[i].z + x[i].w;
  }
  #pragma unroll
  for (int off=32; off>=1; off>>=1) sum += __shfl_xor(sum, off, 64);
  const float mu = sum * (1.f/1024.f);
  float vs = 0.f;
  #pragma unroll
  for (int i=0;i<4;++i){
    float d0=x[i].x-mu, d1=x[i].y-mu, d2=x[i].z-mu, d3=x[i].w-mu;
    vs += d0*d0 + d1*d1 + d2*d2 + d3*d3;
  }
  #pragma unroll
  for (int off=32; off>=1; off>>=1) vs += __shfl_xor(vs, off, 64);
  const float rstd = rsqrtf(vs*(1.f/1024.f) + 1e-5f);
  #pragma unroll
  for (int i=0;i<4;++i){
    const float4 g  = ((const float4*)gamma)[lane + i*64];
    const float4 be = ((const float4*)beta)[lane + i*64];
    float4 y;
    y.x = (x[i].x-mu)*rstd*g.x + be.x;
    y.y = (x[i].y-mu)*rstd*g.y + be.y;
    y.z = (x[i].z-mu)*rstd*g.z + be.z;
    y.w = (x[i].w-mu)*rstd*g.w + be.w;
    ((float4*)(out + (size_t)row*ND))[lane + i*64] = y;
  }
}

// ---------------- launch ----------------
// ws layout (64 MB):
//   [0,8MB)   Wbf: Wq,Wk,Wv,Wo bf16
//   [8,32MB)  Xbf: Qbf,Kbf,Vbf ; later: pm (512B, after gemm_qkv) ; later: proj f32 (16MB)
//   [32,40)   qh bf16 [b,h,s,dk]
//   [40,48)   kh bf16 [b,h,s,dk]
//   [48,56)   vT bf16 [b,h,dk,s]
//   [56,64)   attn bf16 [b,s,d]
extern "C" void kernel_launch(void* const* d_in, const int* in_sizes, int n_in,
                              void* d_out, int out_size, void* d_ws, size_t ws_size,
                              hipStream_t stream){
  const float* Q    = (const float*)d_in[0];
  const float* K    = (const float*)d_in[1];
  const float* V    = (const float*)d_in[2];
  const int*   mask = (const int*)  d_in[3];
  const float* Wq   = (const float*)d_in[4];
  const float* Wk   = (const float*)d_in[5];
  const float* Wv   = (const float*)d_in[6];
  const float* Wo   = (const float*)d_in[7];
  const float* gam  = (const float*)d_in[8];
  const float* bet  = (const float*)d_in[9];
  float* out = (float*)d_out;
  char* ws = (char*)d_ws;

  unsigned short* Wbf  = (unsigned short*)(ws);
  unsigned short* Xbf  = (unsigned short*)(ws + (size_t)(8u<<20));
  unsigned short* qhp  = (unsigned short*)(ws + (size_t)(32u<<20));
  unsigned short* khp  = (unsigned short*)(ws + (size_t)(40u<<20));
  unsigned short* vTp  = (unsigned short*)(ws + (size_t)(48u<<20));
  unsigned short* attb = (unsigned short*)(ws + (size_t)(56u<<20));
  unsigned* pm = (unsigned*)(ws + (size_t)(8u<<20));       // aliases Xbf head, written AFTER gemm_qkv
  float* proj  = (float*)(ws + (size_t)(8u<<20));          // aliases Xbf/pm, written after attn

  cast_bf16<<<4096,256,0,stream>>>(Q, Xbf,                 1<<20);
  cast_bf16<<<4096,256,0,stream>>>(K, Xbf + (1u<<22),      1<<20);
  cast_bf16<<<4096,256,0,stream>>>(V, Xbf + (2u<<22),      1<<20);
  cast_bf16<<<1024,256,0,stream>>>(Wq, Wbf,                1<<18);
  cast_bf16<<<1024,256,0,stream>>>(Wk, Wbf + (1u<<20),     1<<18);
  cast_bf16<<<1024,256,0,stream>>>(Wv, Wbf + (2u<<20),     1<<18);
  cast_bf16<<<1024,256,0,stream>>>(Wo, Wbf + (3u<<20),     1<<18);

  gemm_qkv<<<dim3(8,32,3),256,0,stream>>>((const short*)Xbf, (const short*)Wbf, qhp, khp, vTp);

  maskbits_k<<<16,256,0,stream>>>(mask, pm);

  attn_k<<<256,512,0,stream>>>((const short*)qhp, (const short*)khp, (const short*)vTp, pm, attb);

  gemm_out<<<dim3(8,32),256,0,stream>>>((const short*)attb, (const short*)(Wbf + (3u<<20)), proj);

  ln_k<<<1024,256,0,stream>>>(proj, Q, gam, bet, out);
}